// Round 5
// baseline (1440.248 us; speedup 1.0000x reference)
//
#include <hip/hip_runtime.h>

#define HH 64
#define WW 64
#define CC 128
#define HWSZ 4096   // 64*64

// 4-byte-aligned float pair: compiler may merge to global_load_dwordx2
// (gfx9+ supports dword-aligned multi-dword global loads); if it chooses
// not to, it splits into two dword loads -- correct either way.
struct __attribute__((aligned(4))) f2u { float a, b; };

// ---------------------------------------------------------------------------
// Direct 3x3 conv v3, pad 1, stride 1.
// Block: 256 threads, 32x32 px tile, 4 output channels.
// Thread: 4 consecutive px (x-quad) x 4 oc = 16 acc.
// x staged in LDS (ICC channels, 34x36 rows incl. halo, 16B-aligned reads).
// Weights read from block-uniform addresses -> s_load into SGPRs; they feed
// FMAs as the (single allowed) scalar operand: inner loop = 144 FMA + 6
// ds_read_b128 per ic.  BN_IN fuses relu(bn()) into input staging; STATS
// accumulates per-channel sum/sumsq; ATOMIC = ic-split accumulation.
// ---------------------------------------------------------------------------
template<int TAG, int ICC, bool BN_IN, bool STATS, bool ATOMIC>
__global__ __launch_bounds__(256)
void conv_k(const float* __restrict__ in, const float* __restrict__ wgt,
            const float* __restrict__ bias,
            const float* __restrict__ bnscale, const float* __restrict__ bnshift,
            float* __restrict__ out, float* __restrict__ ssum, float* __restrict__ ssq,
            int oc_total, int ocg_count, int n_split)
{
    __shared__ float xt[ICC][34 * 36];
    const int tid = threadIdx.x;
    const int q  = tid & 7;             // x-quad index, px0 = 4q
    const int ty = tid >> 3;            // 0..31
    const int bx = blockIdx.x * 32, by = blockIdx.y * 32;
    int z = blockIdx.z;
    const int split = z % n_split; z /= n_split;
    const int ocg = z % ocg_count;
    const int b = z / ocg_count;
    const int oc0 = ocg * 4;
    const int icps = CC / n_split;
    const int ic_start = split * icps;

    float acc[4][4];   // [px][oc]
#pragma unroll
    for (int o = 0; o < 4; ++o) {
        float bv = 0.f;
        if (!ATOMIC || split == 0) {
            int oc = min(oc0 + o, oc_total - 1);
            bv = (oc0 + o < oc_total) ? bias[oc] : 0.f;
        }
#pragma unroll
        for (int p = 0; p < 4; ++p) acc[p][o] = bv;
    }

    const float* inb = in + (size_t)b * CC * HWSZ;

    for (int ic0 = ic_start; ic0 < ic_start + icps; ic0 += ICC) {
        __syncthreads();
        for (int i = tid; i < ICC * 34 * 36; i += 256) {
            int ic = i / 1224;
            int rem = i - ic * 1224;
            int r = rem / 36, cl = rem - r * 36;
            int gy = by + r - 1, gx = bx + cl - 1;
            float v = 0.f;
            if (cl < 35 && (unsigned)gy < (unsigned)HH && (unsigned)gx < (unsigned)WW) {
                v = inb[(ic0 + ic) * HWSZ + gy * WW + gx];
                if (BN_IN)
                    v = fmaxf(fmaf(v, bnscale[ic0 + ic], bnshift[ic0 + ic]), 0.f);
            }
            xt[ic][rem] = v;
        }
        __syncthreads();
#pragma unroll
        for (int ic = 0; ic < ICC; ++ic) {
            // weights -> SGPRs (uniform addresses, clamped to stay in-bounds)
            float w[4][9];
#pragma unroll
            for (int o = 0; o < 4; ++o) {
                const float* wp = wgt + ((size_t)min(oc0 + o, oc_total - 1) * CC + (ic0 + ic)) * 9;
                bool valid = (oc0 + o < oc_total);
#pragma unroll
                for (int k = 0; k < 9; ++k)
                    w[o][k] = valid ? wp[k] : 0.f;
            }
            // window: 2 x b128 per row, 3 rows
            float win[3][8];
#pragma unroll
            for (int ky = 0; ky < 3; ++ky) {
                const float4* rp = reinterpret_cast<const float4*>(&xt[ic][(ty + ky) * 36 + 4 * q]);
                float4 lo = rp[0], hi = rp[1];
                win[ky][0] = lo.x; win[ky][1] = lo.y; win[ky][2] = lo.z; win[ky][3] = lo.w;
                win[ky][4] = hi.x; win[ky][5] = hi.y; win[ky][6] = hi.z; win[ky][7] = hi.w;
            }
#pragma unroll
            for (int k = 0; k < 9; ++k) {
                const int ky = k / 3, kx = k % 3;
#pragma unroll
                for (int o = 0; o < 4; ++o)
#pragma unroll
                    for (int p = 0; p < 4; ++p)
                        acc[p][o] = fmaf(win[ky][p + kx], w[o][k], acc[p][o]);
            }
        }
    }

    const int py = by + ty;
    const int px0 = bx + 4 * q;
#pragma unroll
    for (int o = 0; o < 4; ++o) {
        int oc = oc0 + o;
        if (ATOMIC) {
            if (oc < oc_total) {
                float* op = out + ((size_t)b * oc_total + oc) * HWSZ + py * WW + px0;
#pragma unroll
                for (int p = 0; p < 4; ++p) atomicAdd(op + p, acc[p][o]);
            }
        } else {
            float4 v = make_float4(acc[0][o], acc[1][o], acc[2][o], acc[3][o]);
            *reinterpret_cast<float4*>(out + ((size_t)b * oc_total + oc) * HWSZ + py * WW + px0) = v;
        }
    }

    if (STATS) {
#pragma unroll
        for (int o = 0; o < 4; ++o) {
            float s = acc[0][o] + acc[1][o] + acc[2][o] + acc[3][o];
            float qq = acc[0][o] * acc[0][o] + acc[1][o] * acc[1][o]
                     + acc[2][o] * acc[2][o] + acc[3][o] * acc[3][o];
            for (int d = 32; d > 0; d >>= 1) {
                s  += __shfl_down(s, d);
                qq += __shfl_down(qq, d);
            }
            if ((tid & 63) == 0) {
                atomicAdd(&ssum[oc0 + o], s);
                atomicAdd(&ssq[oc0 + o], qq);
            }
        }
    }
}

// ---------------------------------------------------------------------------
// Deformable 3x3 conv v3 (deform_groups=1, pad 1, stride 1, zero-pad).
// R1's global-gather structure (zero bank conflicts) with the gather count
// halved: bilinear corner pairs (v00,v01) and (v10,v11) are column-adjacent,
// loaded as one float2 each (18 loads/ic instead of 36).  Border columns are
// resolved with selects; validity-folded weights zero any junk lane.
// Weights from block-uniform addresses -> SGPRs.  1 px x 16 oc per thread.
// ---------------------------------------------------------------------------
__global__ __launch_bounds__(256)
void dconv_k(const float* __restrict__ x, const float* __restrict__ off,
             const float* __restrict__ wd, const float* __restrict__ bd,
             float* __restrict__ dout)
{
    const int tid = threadIdx.x;
    const int tx = tid & 15, ty = tid >> 4;
    const int px = blockIdx.x * 16 + tx;
    const int py = blockIdx.y * 16 + ty;
    const int b = blockIdx.z >> 3;
    const int oc0 = (blockIdx.z & 7) * 16;

    int   iA[9], iB[9];
    float w00[9], w01[9], w10[9], w11[9], shf[9];
    const float* offb = off + (size_t)b * 18 * HWSZ + py * WW + px;
#pragma unroll
    for (int k = 0; k < 9; ++k) {
        float dyv = offb[(2 * k + 0) * HWSZ];
        float dxv = offb[(2 * k + 1) * HWSZ];
        float fy = (float)(py + k / 3 - 1) + dyv;
        float fx = (float)(px + k % 3 - 1) + dxv;
        float yl = floorf(fy), xl = floorf(fx);
        float ly = fy - yl, lx = fx - xl;
        int iy0 = (int)yl, ix0 = (int)xl;
        int iy1 = iy0 + 1, ix1 = ix0 + 1;
        float vy0 = (iy0 >= 0 && iy0 < HH) ? 1.f : 0.f;
        float vy1 = (iy1 >= 0 && iy1 < HH) ? 1.f : 0.f;
        float vx0 = (ix0 >= 0 && ix0 < WW) ? 1.f : 0.f;
        float vx1 = (ix1 >= 0 && ix1 < WW) ? 1.f : 0.f;
        int cx = min(max(ix0, 0), WW - 2);          // aligned-pair base col
        shf[k] = (float)(ix0 - cx);                 // -2..2; only +-1 matters
        int ry0 = min(max(iy0, 0), HH - 1) * WW;
        int ry1 = min(max(iy1, 0), HH - 1) * WW;
        iA[k] = ry0 + cx;
        iB[k] = ry1 + cx;
        w00[k] = (1.f - ly) * (1.f - lx) * vy0 * vx0;
        w01[k] = (1.f - ly) * lx         * vy0 * vx1;
        w10[k] = ly * (1.f - lx) * vy1 * vx0;
        w11[k] = ly * lx         * vy1 * vx1;
    }

    float acc[16];
#pragma unroll
    for (int o = 0; o < 16; ++o) acc[o] = bd[oc0 + o];

    const float* xb = x + (size_t)b * CC * HWSZ;
#pragma unroll 2
    for (int ic = 0; ic < CC; ++ic) {
        const float* xc = xb + ic * HWSZ;
        const float* wp = wd + ((size_t)oc0 * CC + ic) * 9;   // uniform -> s_load
#pragma unroll
        for (int k = 0; k < 9; ++k) {
            f2u pa = *reinterpret_cast<const f2u*>(xc + iA[k]);
            f2u pb = *reinterpret_cast<const f2u*>(xc + iB[k]);
            float v00 = (shf[k] ==  1.f) ? pa.b : pa.a;
            float v01 = (shf[k] == -1.f) ? pa.a : pa.b;
            float v10 = (shf[k] ==  1.f) ? pb.b : pb.a;
            float v11 = (shf[k] == -1.f) ? pb.a : pb.b;
            float s =      w00[k] * v00;
            s = fmaf(w01[k], v01, s);
            s = fmaf(w10[k], v10, s);
            s = fmaf(w11[k], v11, s);
#pragma unroll
            for (int o = 0; o < 16; ++o)
                acc[o] = fmaf(s, wp[o * CC * 9 + k], acc[o]);
        }
    }

    float* ob = dout + ((size_t)b * CC + oc0) * HWSZ + py * WW + px;
#pragma unroll
    for (int o = 0; o < 16; ++o)
        ob[o * HWSZ] = acc[o];
}

// mean/var -> (scale, shift) per channel
__global__ void bnstat_k(const float* __restrict__ ssum, const float* __restrict__ ssq,
                         const float* __restrict__ g, const float* __restrict__ bet,
                         float* __restrict__ scale, float* __restrict__ shift)
{
    int c = threadIdx.x;
    const float invn = 1.f / (4.f * HWSZ);
    float mean = ssum[c] * invn;
    float var  = ssq[c] * invn - mean * mean;
    float sc = g[c] * rsqrtf(var + 1e-5f);
    scale[c] = sc;
    shift[c] = fmaf(-mean, sc, bet[c]);
}

// out = relu(dout + bn2(y2)), vectorized float4
__global__ __launch_bounds__(256)
void final_k(const float* __restrict__ dout, const float* __restrict__ y2,
             const float* __restrict__ scale, const float* __restrict__ shift,
             float* __restrict__ out)
{
    int i = blockIdx.x * 256 + threadIdx.x;       // over 2M/4 float4s
    int c = (i >> 10) & 127;                      // channel of this float4
    float4 d = reinterpret_cast<const float4*>(dout)[i];
    float4 y = reinterpret_cast<const float4*>(y2)[i];
    float sc = scale[c], sh = shift[c];
    float4 r;
    r.x = fmaxf(d.x + fmaf(y.x, sc, sh), 0.f);
    r.y = fmaxf(d.y + fmaf(y.y, sc, sh), 0.f);
    r.z = fmaxf(d.z + fmaf(y.z, sc, sh), 0.f);
    r.w = fmaxf(d.w + fmaf(y.w, sc, sh), 0.f);
    reinterpret_cast<float4*>(out)[i] = r;
}

extern "C" void kernel_launch(void* const* d_in, const int* in_sizes, int n_in,
                              void* d_out, int out_size, void* d_ws, size_t ws_size,
                              hipStream_t stream)
{
    const float* x     = (const float*)d_in[0];
    const float* w_off = (const float*)d_in[1];
    const float* b_off = (const float*)d_in[2];
    const float* w_d   = (const float*)d_in[3];
    const float* b_d   = (const float*)d_in[4];
    const float* w1    = (const float*)d_in[5];
    const float* b1    = (const float*)d_in[6];
    const float* g1    = (const float*)d_in[7];
    const float* be1   = (const float*)d_in[8];
    const float* w2    = (const float*)d_in[9];
    const float* b2    = (const float*)d_in[10];
    const float* g2    = (const float*)d_in[11];
    const float* be2   = (const float*)d_in[12];

    float* ws      = (float*)d_ws;
    float* off_buf = ws;                      // B*18*H*W       = 294912
    float* y1      = off_buf + 294912;        // B*C*H*W        = 2097152
    float* y2      = y1 + 2097152;
    float* dob     = y2 + 2097152;
    float* st      = dob + 2097152;           // stats/params
    // st: sum1[128] sq1[128] sum2[128] sq2[128] scale1[128] shift1[128] scale2[128] shift2[128]

    hipMemsetAsync(off_buf, 0, 294912 * sizeof(float), stream);
    hipMemsetAsync(st, 0, 512 * sizeof(float), stream);

    // offset conv: 18 oc (5 groups of 4), ic-split 4, atomic accumulate
    conv_k<0, 8, false, false, true><<<dim3(2, 2, 4 * 5 * 4), 256, 0, stream>>>(
        x, w_off, b_off, nullptr, nullptr, off_buf, nullptr, nullptr, 18, 5, 4);

    // deformable conv -> dob
    dconv_k<<<dim3(4, 4, 32), 256, 0, stream>>>(x, off_buf, w_d, b_d, dob);

    // conv1 (+ BN1 stats) -> y1
    conv_k<1, 8, false, true, false><<<dim3(2, 2, 4 * 32), 256, 0, stream>>>(
        x, w1, b1, nullptr, nullptr, y1, st, st + 128, 128, 32, 1);
    bnstat_k<<<1, 128, 0, stream>>>(st, st + 128, g1, be1, st + 512, st + 640);

    // conv2 on relu(bn1(y1)) fused into staging (+ BN2 stats) -> y2
    conv_k<2, 8, true, true, false><<<dim3(2, 2, 4 * 32), 256, 0, stream>>>(
        y1, w2, b2, st + 512, st + 640, y2, st + 256, st + 384, 128, 32, 1);
    bnstat_k<<<1, 128, 0, stream>>>(st + 256, st + 384, g2, be2, st + 768, st + 896);

    // out = relu(dob + bn2(y2))
    final_k<<<dim3(2048), 256, 0, stream>>>(dob, y2, st + 768, st + 896, (float*)d_out);
}